// Round 9
// baseline (452.111 us; speedup 1.0000x reference)
//
#include <hip/hip_runtime.h>

#define NPT    4096
#define NBATCH 16
#define NS     512
#define KSAMP  32
#define MROWS  (NBATCH*NS*KSAMP)   // 262144
#define RC2    0.04f
#define NZSTAT 3288                // doubles to zero: 216 + 512 + 512 + 1024 + 1024

using bf16x8 = __attribute__((ext_vector_type(8))) short;
using f32x4  = __attribute__((ext_vector_type(4))) float;
using f32x2  = __attribute__((ext_vector_type(2))) float;
#define MFMA16(A,B,C) __builtin_amdgcn_mfma_f32_16x16x32_bf16(A,B,C,0,0,0)

__device__ __forceinline__ unsigned short f2bf(float f) {
  unsigned u = __float_as_uint(f);
  unsigned r = (u + 0x7FFFu + ((u >> 16) & 1u)) >> 16;   // RNE
  return (unsigned short)r;
}
__device__ __forceinline__ float bf2f(unsigned short h) {
  return __uint_as_float(((unsigned)h) << 16);
}
__device__ __forceinline__ void atomAddF64(double* p, double v) {
  unsafeAtomicAdd(p, v);   // hw global_atomic_add_f64
}

// Packed f32 math (VOP3P). Compiler scalarizes f32x2 arithmetic (R3 evidence);
// these force v_pk_* — IEEE-rn per element, bit-identical to scalar ops.
__device__ __forceinline__ f32x2 pk_add(f32x2 a, f32x2 b) {
  f32x2 r; asm("v_pk_add_f32 %0, %1, %2" : "=v"(r) : "v"(a), "v"(b)); return r;
}
__device__ __forceinline__ f32x2 pk_mul(f32x2 a, f32x2 b) {
  f32x2 r; asm("v_pk_mul_f32 %0, %1, %2" : "=v"(r) : "v"(a), "v"(b)); return r;
}

// f64-keyed max with DPP source (key hi-word = dist bits >= 0 so u64 order ==
// f64 order). old=0, bound_ctrl=1: disabled/missing lanes contribute 0 (=id).
template<int CTRL>
__device__ __forceinline__ double dpp_max(double v) {
  long long x = __double_as_longlong(v);
  int lo = __builtin_amdgcn_update_dpp(0, (int)(x & 0xFFFFFFFFll), CTRL, 0xf, 0xf, true);
  int hi = __builtin_amdgcn_update_dpp(0, (int)(x >> 32),          CTRL, 0xf, 0xf, true);
  return fmax(v, __hiloint2double(hi, lo));
}

// ---------------------------------------------------------------------------
// K1: blocks 0..15 = FPS (one per batch, 512 thr = 2 waves/SIMD, 8 pts/thread
// as 4 f32x2). Distance update via v_pk_add/mul (sub done as add of negated
// centroid — negation exact, rn identical). Centroid lookup via float4 LDS
// table (one broadcast ds_read_b128 instead of 3x b32 on the serial chain).
// Reduce: DPP wave reduce (lane63) -> plain ds_write_b64 to parity slot
// red[s&1][w] -> ONE barrier -> all threads read 8 slots + 7-max f64 tree.
// [R5-measured tail; R6/R7's two-barrier wave0 tail was slower — keep.]
// Block 16 = weight bf16 conversion + zeroing of the f64 stats region.
// ---------------------------------------------------------------------------
__global__ __launch_bounds__(512) void fps_wconv_kernel(const float* __restrict__ xyz,
                                                        float* __restrict__ out_newxyz,
                                                        float* __restrict__ ws_newxyz,
                                                        const float* __restrict__ w0,
                                                        const float* __restrict__ w1,
                                                        const float* __restrict__ w2,
                                                        unsigned short* __restrict__ wbf0,
                                                        unsigned short* __restrict__ wbf1,
                                                        unsigned short* __restrict__ wbf2,
                                                        double* __restrict__ statz)
{
  const int t = threadIdx.x;
  const int b = blockIdx.x;
  if (b == NBATCH) {
    if (t < 64) {
#pragma unroll
      for (int c = 0; c < 8; ++c)
        wbf0[t*8 + c] = (c < 6) ? f2bf(w0[t*6 + c]) : (unsigned short)0;
    }
    for (int i = t; i < 64*64; i += 512) wbf1[i] = f2bf(w1[i]);
    for (int i = t; i < 128*64; i += 512) wbf2[i] = f2bf(w2[i]);
    for (int i = t; i < NZSTAT; i += 512) statz[i] = 0.0;
    return;
  }

  __shared__ float pts[NPT*3];                 // staging only
  __shared__ __align__(16) float4 ptsv[NPT];   // hot lookup table
  __shared__ float cent[NS*3];
  __shared__ __align__(16) double red[2][8];
  const float* xb = xyz + (size_t)b * NPT * 3;

  { const float4* s4 = (const float4*)xb;
    float4* d4 = (float4*)pts;
    for (int i = t; i < NPT*3/4; i += 512) d4[i] = s4[i]; }
  __syncthreads();
  for (int i = t; i < NPT; i += 512)
    ptsv[i] = float4{pts[i*3+0], pts[i*3+1], pts[i*3+2], 0.f};
  __syncthreads();

  f32x2 px[4], py[4], pz[4], dist[4];
  unsigned int loc0[4], loc1[4];
#pragma unroll
  for (int j = 0; j < 4; ++j) {
    int i0 = t + (2*j)   * 512;
    int i1 = t + (2*j+1) * 512;
    float4 p0 = ptsv[i0], p1 = ptsv[i1];
    px[j] = f32x2{p0.x, p1.x};
    py[j] = f32x2{p0.y, p1.y};
    pz[j] = f32x2{p0.z, p1.z};
    dist[j] = f32x2{1e10f, 1e10f};
    loc0[j] = ~(unsigned)i0;
    loc1[j] = ~(unsigned)i1;
  }

  const int lane = t & 63, w = t >> 6;
  int far = 0;
  for (int s = 0; s < NS; ++s) {
    const float4 c4 = ptsv[far];               // one broadcast b128
    if (t == 0) { cent[s*3+0] = c4.x; cent[s*3+1] = c4.y; cent[s*3+2] = c4.z; }
    if (s == NS-1) break;

    double kk[8];
    {
      // sub as add-of-negated-centroid: negation exact, rn(a+(-c))==rn(a-c)
      const f32x2 ncx = {-c4.x, -c4.x}, ncy = {-c4.y, -c4.y}, ncz = {-c4.z, -c4.z};
#pragma unroll
      for (int j = 0; j < 4; ++j) {
        f32x2 dx = pk_add(px[j], ncx);
        f32x2 dy = pk_add(py[j], ncy);
        f32x2 dz = pk_add(pz[j], ncz);
        // numpy order: (dx*dx + dy*dy) + dz*dz, rn each op, no contraction
        f32x2 dd = pk_add(pk_add(pk_mul(dx,dx), pk_mul(dy,dy)), pk_mul(dz,dz));
        f32x2 nd;
        nd.x = fminf(dist[j].x, dd.x);
        nd.y = fminf(dist[j].y, dd.y);
        dist[j] = nd;
        unsigned long long k0 = ((unsigned long long)__float_as_uint(nd.x) << 32)
                              | (unsigned long long)loc0[j];
        unsigned long long k1 = ((unsigned long long)__float_as_uint(nd.y) << 32)
                              | (unsigned long long)loc1[j];
        kk[2*j]   = __longlong_as_double((long long)k0);
        kk[2*j+1] = __longlong_as_double((long long)k1);
      }
    }
    // depth-3 max tree (max is associative: order-independent result)
    double best = fmax(fmax(fmax(kk[0], kk[1]), fmax(kk[2], kk[3])),
                       fmax(fmax(kk[4], kk[5]), fmax(kk[6], kk[7])));
    best = dpp_max<0x111>(best);   // row_shr:1
    best = dpp_max<0x112>(best);   // row_shr:2
    best = dpp_max<0x114>(best);   // row_shr:4
    best = dpp_max<0x118>(best);   // row_shr:8
    best = dpp_max<0x142>(best);   // row_bcast:15
    best = dpp_max<0x143>(best);   // row_bcast:31 -> lane63 = wave max

    if (lane == 63) red[s & 1][w] = best;      // plain b64 write, own slot
    __syncthreads();
    { const double2* r2 = (const double2*)red[s & 1];
      double2 a = r2[0], b2 = r2[1], c = r2[2], d = r2[3];
      double m = fmax(fmax(fmax(a.x, a.y), fmax(b2.x, b2.y)),
                      fmax(fmax(c.x, c.y), fmax(d.x, d.y)));
      far = (int)(~(unsigned)(unsigned long long)__double_as_longlong(m));
    }
  }
  __syncthreads();
  for (int i = t; i < NS*3; i += 512) {
    float v = cent[i];
    out_newxyz[(size_t)b*NS*3 + i] = v;
    ws_newxyz[(size_t)b*NS*3 + i]  = v;
  }
}

// ---------------------------------------------------------------------------
// K2: ball query (first-32-by-index within radius, pad with first), gather,
// write feats bf16 [262144][8], accumulate moments of the ROUNDED values into
// 8 f64 buckets via hw atomics. Distance exactly replicates numpy op order.
// ---------------------------------------------------------------------------
__global__ __launch_bounds__(256) void ball_kernel(const float* __restrict__ xyz,
                                                   const float* __restrict__ pointsf,
                                                   const float* __restrict__ ws_newxyz,
                                                   unsigned short* __restrict__ featsbf,
                                                   double* __restrict__ momb)
{
  __shared__ int sel[4][KSAMP];
  __shared__ float momw[4][27];
  const int t = threadIdx.x, lane = t & 63, w = t >> 6;
  const int q = blockIdx.x * 4 + w;         // 0..8191
  const int b = q >> 9;
  const float* xb = xyz     + (size_t)b * NPT * 3;
  const float* pb = pointsf + (size_t)b * NPT * 3;

  const float qx = ws_newxyz[q*3+0], qy = ws_newxyz[q*3+1], qz = ws_newxyz[q*3+2];
  const float q2 = __fadd_rn(__fadd_rn(__fmul_rn(qx,qx), __fmul_rn(qy,qy)), __fmul_rn(qz,qz));

  int count = 0;
  for (int c = 0; c < 64 && count < KSAMP; ++c) {
    int i = (c << 6) + lane;
    float fx = xb[i*3+0], fy = xb[i*3+1], fz = xb[i*3+2];
    float p2 = __fadd_rn(__fadd_rn(__fmul_rn(fx,fx), __fmul_rn(fy,fy)), __fmul_rn(fz,fz));
    float e  = __fadd_rn(__fadd_rn(__fmul_rn(qx,fx), __fmul_rn(qy,fy)), __fmul_rn(qz,fz));
    float d  = __fadd_rn(__fadd_rn(__fmul_rn(-2.0f, e), q2), p2);
    bool keep = (d <= RC2);
    unsigned long long mask = __ballot(keep ? 1 : 0);
    int slot = count + (int)__popcll(mask & ((1ull << lane) - 1ull));
    if (keep && slot < KSAMP) sel[w][slot] = i;
    count += (int)__popcll(mask);
  }
  __syncthreads();

  float f[6];
  const int n = (count < KSAMP) ? count : KSAMP;
  if (lane < KSAMP) {
    int id = (lane < n) ? sel[w][lane] : sel[w][0];
    float gx = xb[id*3+0], gy = xb[id*3+1], gz = xb[id*3+2];
    unsigned short hb[8];
    hb[0] = f2bf(__fsub_rn(gx, qx));
    hb[1] = f2bf(__fsub_rn(gy, qy));
    hb[2] = f2bf(__fsub_rn(gz, qz));
    hb[3] = f2bf(pb[id*3+0]);
    hb[4] = f2bf(pb[id*3+1]);
    hb[5] = f2bf(pb[id*3+2]);
    uint4 pk;
    pk.x = (unsigned)hb[0] | ((unsigned)hb[1] << 16);
    pk.y = (unsigned)hb[2] | ((unsigned)hb[3] << 16);
    pk.z = (unsigned)hb[4] | ((unsigned)hb[5] << 16);
    pk.w = 0;
    ((uint4*)featsbf)[(size_t)q * KSAMP + lane] = pk;
#pragma unroll
    for (int c2 = 0; c2 < 6; ++c2) f[c2] = bf2f(hb[c2]);
  } else {
    f[0]=f[1]=f[2]=f[3]=f[4]=f[5]=0.f;
  }

  float p[27];
#pragma unroll
  for (int c = 0; c < 6; ++c) p[c] = f[c];
  { int m = 6;
#pragma unroll
    for (int c = 0; c < 6; ++c)
#pragma unroll
      for (int d = c; d < 6; ++d) p[m++] = f[c]*f[d]; }
#pragma unroll
  for (int mm = 0; mm < 27; ++mm) {
    float v = p[mm];
#pragma unroll
    for (int off = 1; off < 64; off <<= 1) v += __shfl_xor(v, off);
    p[mm] = v;
  }
  if (lane == 0) {
#pragma unroll
    for (int mm = 0; mm < 27; ++mm) momw[w][mm] = p[mm];
  }
  __syncthreads();
  if (t < 27)
    atomAddF64(&momb[(blockIdx.x & 7)*27 + t],
               (double)(momw[0][t] + momw[1][t] + momw[2][t] + momw[3][t]));
}

// ---------------------------------------------------------------------------
// MLP via bf16 MFMA 16x16x32. Block = 256 rows (8 queries), 4 waves.
// Per-block BN scale/shift prologue from global f64 stat buckets:
//   L0: analytic from 27 moments of rounded feats x rounded W0.
//   L1/L2: mean/var from bucketed sum/sumsq of raw accumulators.
// PASS 1: L0,L1 -> bucket-atomics stats(L1).
// PASS 2: L0,L1,L2 -> bucket-atomics stats(L2).
// PASS 3: L0,L1,L2 -> bn2+relu+max over k=32 -> out.
// ---------------------------------------------------------------------------
template<int PASS>
__global__ __launch_bounds__(256) void mlp_kernel(
    const unsigned short* __restrict__ featsbf,
    const unsigned short* __restrict__ wbf0,
    const unsigned short* __restrict__ wbf1,
    const unsigned short* __restrict__ wbf2,
    const double* __restrict__ momb,
    const float* __restrict__ g0, const float* __restrict__ be0,
    const float* __restrict__ g1, const float* __restrict__ be1,
    const float* __restrict__ g2, const float* __restrict__ be2,
    double* __restrict__ s1g, double* __restrict__ q1g,
    double* __restrict__ s2g, double* __restrict__ q2g,
    float* __restrict__ outp)
{
  __shared__ __align__(16) unsigned short xb[256*72];   // 36864 B
  __shared__ __align__(16) unsigned short wb[128*72];   // 18432 B
  constexpr int SN = (PASS==1) ? 4*64 : (PASS==2 ? 4*128 : 1);
  __shared__ float ssum[SN], sqsum[SN];
  __shared__ float ssc0[64], ssh0[64], ssc1[64], ssh1[64], ssc2[128], ssh2[128];
  __shared__ double mom[27];

  unsigned short* wb0 = wb + 64*72;   // [64][8]  bf16 overlay
  unsigned short* xf  = wb + 72*72;   // [256][8] bf16 overlay

  const int t = threadIdx.x, blk = blockIdx.x;
  const int lane = t & 63, w = t >> 6;
  const int lr = lane & 15, lk = lane >> 4;

  // ---- staging + moment bucket sum ----
  ((uint4*)xf)[t] = ((const uint4*)featsbf)[(size_t)blk*256 + t];
  if (t < 64) ((uint4*)wb0)[t] = ((const uint4*)wbf0)[t];
  { int row = t >> 2, seg = t & 3;   // W1: 64 rows x 128 B
    const uint4* src = (const uint4*)(wbf1 + row*64 + seg*16);
    uint4* dst = (uint4*)(wb + row*72 + seg*16);
    dst[0] = src[0]; dst[1] = src[1]; }
  if (t < 27) {
    double s = 0.0;
#pragma unroll
    for (int bkt = 0; bkt < 8; ++bkt) s += momb[bkt*27 + t];
    mom[t] = s / (double)MROWS;
  }
  __syncthreads();

  // ---- per-block BN scale/shift prologue ----
  if (t < 64) {
    double wv[6];
#pragma unroll
    for (int c = 0; c < 6; ++c) wv[c] = (double)bf2f(wbf0[t*8 + c]);
    double macc = 0.0;
#pragma unroll
    for (int c = 0; c < 6; ++c) macc += wv[c] * mom[c];
    double e2 = 0.0;
    int mi = 6;
#pragma unroll
    for (int c = 0; c < 6; ++c)
#pragma unroll
      for (int d = c; d < 6; ++d) {
        double coef = (c == d) ? wv[c]*wv[c] : 2.0*wv[c]*wv[d];
        e2 += coef * mom[mi++];
      }
    double var = e2 - macc*macc;
    float sc = g0[t] / sqrtf((float)var + 1e-5f);
    ssc0[t] = sc;
    ssh0[t] = be0[t] - (float)macc * sc;
  }
  if (PASS >= 2 && t < 64) {
    double s = 0.0, qq = 0.0;
#pragma unroll
    for (int bkt = 0; bkt < 8; ++bkt) { s += s1g[bkt*64 + t]; qq += q1g[bkt*64 + t]; }
    double mean = s / (double)MROWS;
    double var  = qq / (double)MROWS - mean*mean;
    float sc = g1[t] / sqrtf((float)var + 1e-5f);
    ssc1[t] = sc;
    ssh1[t] = be1[t] - (float)mean * sc;
  }
  if (PASS == 3 && t < 128) {
    double s = 0.0, qq = 0.0;
#pragma unroll
    for (int bkt = 0; bkt < 8; ++bkt) { s += s2g[bkt*128 + t]; qq += q2g[bkt*128 + t]; }
    double mean = s / (double)MROWS;
    double var  = qq / (double)MROWS - mean*mean;
    float sc = g2[t] / sqrtf((float)var + 1e-5f);
    ssc2[t] = sc;
    ssh2[t] = be2[t] - (float)mean * sc;
  }
  __syncthreads();

  const bf16x8 zb = {0,0,0,0,0,0,0,0};
  const f32x4 fz = {0.f,0.f,0.f,0.f};

  // ---- L0 ----
  f32x4 acc[16];
#pragma unroll
  for (int i = 0; i < 16; ++i) acc[i] = fz;
  {
    bf16x8 af[4], bw[4];
#pragma unroll
    for (int i = 0; i < 4; ++i) { af[i] = zb; bw[i] = zb; }
    if (lk == 0) {
#pragma unroll
      for (int rt = 0; rt < 4; ++rt) af[rt] = *(const bf16x8*)&xf[(w*64 + rt*16 + lr)*8];
#pragma unroll
      for (int ct = 0; ct < 4; ++ct) bw[ct] = *(const bf16x8*)&wb0[(ct*16 + lr)*8];
    }
#pragma unroll
    for (int rt = 0; rt < 4; ++rt)
#pragma unroll
      for (int ct = 0; ct < 4; ++ct) acc[rt*4+ct] = MFMA16(af[rt], bw[ct], acc[rt*4+ct]);
  }
#pragma unroll
  for (int rt = 0; rt < 4; ++rt)
#pragma unroll
    for (int ct = 0; ct < 4; ++ct) {
      const int ch = ct*16 + lr;
      const float sc = ssc0[ch], sh = ssh0[ch];
#pragma unroll
      for (int r = 0; r < 4; ++r) {
        const int row = w*64 + rt*16 + lk*4 + r;
        float v = fmaxf(fmaf(acc[rt*4+ct][r], sc, sh), 0.f);
        xb[row*72 + ch] = f2bf(v);
      }
    }
  __syncthreads();

  // ---- L1 ----
  f32x4 acc1[16];
#pragma unroll
  for (int i = 0; i < 16; ++i) acc1[i] = fz;
#pragma unroll
  for (int k0 = 0; k0 < 64; k0 += 32) {
    bf16x8 af[4], bw[4];
#pragma unroll
    for (int rt = 0; rt < 4; ++rt) af[rt] = *(const bf16x8*)&xb[(w*64 + rt*16 + lr)*72 + k0 + lk*8];
#pragma unroll
    for (int ct = 0; ct < 4; ++ct) bw[ct] = *(const bf16x8*)&wb[(ct*16 + lr)*72 + k0 + lk*8];
#pragma unroll
    for (int rt = 0; rt < 4; ++rt)
#pragma unroll
      for (int ct = 0; ct < 4; ++ct) acc1[rt*4+ct] = MFMA16(af[rt], bw[ct], acc1[rt*4+ct]);
  }

  if constexpr (PASS == 1) {
#pragma unroll
    for (int ct = 0; ct < 4; ++ct) {
      float s = 0.f, q = 0.f;
#pragma unroll
      for (int rt = 0; rt < 4; ++rt)
#pragma unroll
        for (int r = 0; r < 4; ++r) { float v = acc1[rt*4+ct][r]; s += v; q = fmaf(v, v, q); }
      s += __shfl_xor(s, 16); s += __shfl_xor(s, 32);
      q += __shfl_xor(q, 16); q += __shfl_xor(q, 32);
      if (lk == 0) { ssum[w*64 + ct*16 + lr] = s; sqsum[w*64 + ct*16 + lr] = q; }
    }
    __syncthreads();
    if (t < 64) {
      float s = ssum[t] + ssum[64+t] + ssum[128+t] + ssum[192+t];
      float q = sqsum[t] + sqsum[64+t] + sqsum[128+t] + sqsum[192+t];
      const int bkt = blk & 7;
      atomAddF64(&s1g[bkt*64 + t], (double)s);
      atomAddF64(&q1g[bkt*64 + t], (double)q);
    }
    return;
  }

  __syncthreads();

  { int row = t >> 1, seg = t & 1;   // W2: 128 rows x 128 B
    const uint4* src = (const uint4*)(wbf2 + row*64 + seg*32);
    uint4* dst = (uint4*)(wb + row*72 + seg*32);
    dst[0] = src[0]; dst[1] = src[1]; dst[2] = src[2]; dst[3] = src[3]; }
#pragma unroll
  for (int rt = 0; rt < 4; ++rt)
#pragma unroll
    for (int ct = 0; ct < 4; ++ct) {
      const int ch = ct*16 + lr;
      const float sc = ssc1[ch], sh = ssh1[ch];
#pragma unroll
      for (int r = 0; r < 4; ++r) {
        const int row = w*64 + rt*16 + lk*4 + r;
        float v = fmaxf(fmaf(acc1[rt*4+ct][r], sc, sh), 0.f);
        xb[row*72 + ch] = f2bf(v);
      }
    }
  __syncthreads();

  // ---- L2 ----
#pragma unroll
  for (int half = 0; half < 2; ++half) {
    f32x4 acc2[16];
#pragma unroll
    for (int i = 0; i < 16; ++i) acc2[i] = fz;
#pragma unroll
    for (int k0 = 0; k0 < 64; k0 += 32) {
      bf16x8 af[4], bw[4];
#pragma unroll
      for (int rt = 0; rt < 4; ++rt) af[rt] = *(const bf16x8*)&xb[(w*64 + rt*16 + lr)*72 + k0 + lk*8];
#pragma unroll
      for (int ct = 0; ct < 4; ++ct) bw[ct] = *(const bf16x8*)&wb[((half*4+ct)*16 + lr)*72 + k0 + lk*8];
#pragma unroll
      for (int rt = 0; rt < 4; ++rt)
#pragma unroll
        for (int ct = 0; ct < 4; ++ct) acc2[rt*4+ct] = MFMA16(af[rt], bw[ct], acc2[rt*4+ct]);
    }
    if constexpr (PASS == 2) {
#pragma unroll
      for (int ct = 0; ct < 4; ++ct) {
        float s = 0.f, q = 0.f;
#pragma unroll
        for (int rt = 0; rt < 4; ++rt)
#pragma unroll
          for (int r = 0; r < 4; ++r) { float v = acc2[rt*4+ct][r]; s += v; q = fmaf(v, v, q); }
        s += __shfl_xor(s, 16); s += __shfl_xor(s, 32);
        q += __shfl_xor(q, 16); q += __shfl_xor(q, 32);
        const int ch = (half*4+ct)*16 + lr;
        if (lk == 0) { ssum[w*128 + ch] = s; sqsum[w*128 + ch] = q; }
      }
    } else {
#pragma unroll
      for (int ct = 0; ct < 4; ++ct) {
        const int ch = (half*4+ct)*16 + lr;
        const float sc = ssc2[ch], sh = ssh2[ch];
        float ma = 0.f, mb = 0.f;   // relu floor
#pragma unroll
        for (int r = 0; r < 4; ++r) {
          ma = fmaxf(ma, fmaf(acc2[0*4+ct][r], sc, sh));
          ma = fmaxf(ma, fmaf(acc2[1*4+ct][r], sc, sh));
          mb = fmaxf(mb, fmaf(acc2[2*4+ct][r], sc, sh));
          mb = fmaxf(mb, fmaf(acc2[3*4+ct][r], sc, sh));
        }
        ma = fmaxf(ma, __shfl_xor(ma, 16)); ma = fmaxf(ma, __shfl_xor(ma, 32));
        mb = fmaxf(mb, __shfl_xor(mb, 16)); mb = fmaxf(mb, __shfl_xor(mb, 32));
        if (lk == 0) {
          const int q0 = blk*8 + w*2;
          outp[(size_t)q0*128 + ch]     = ma;
          outp[(size_t)(q0+1)*128 + ch] = mb;
        }
      }
    }
  }
  if constexpr (PASS == 2) {
    __syncthreads();
    if (t < 128) {
      float s = ssum[t] + ssum[128+t] + ssum[256+t] + ssum[384+t];
      float q = sqsum[t] + sqsum[128+t] + sqsum[256+t] + sqsum[384+t];
      const int bkt = blk & 7;
      atomAddF64(&s2g[bkt*128 + t], (double)s);
      atomAddF64(&q2g[bkt*128 + t], (double)q);
    }
  }
}

// ---------------------------------------------------------------------------
extern "C" void kernel_launch(void* const* d_in, const int* in_sizes, int n_in,
                              void* d_out, int out_size, void* d_ws, size_t ws_size,
                              hipStream_t stream)
{
  const float* xyz     = (const float*)d_in[0];
  const float* pointsf = (const float*)d_in[1];
  const float* w0  = (const float*)d_in[2];
  const float* g0  = (const float*)d_in[4];
  const float* be0 = (const float*)d_in[5];
  const float* w1  = (const float*)d_in[6];
  const float* g1  = (const float*)d_in[8];
  const float* be1 = (const float*)d_in[9];
  const float* w2  = (const float*)d_in[10];
  const float* g2  = (const float*)d_in[12];
  const float* be2 = (const float*)d_in[13];

  float* out        = (float*)d_out;
  float* out_newxyz = out;            // 16*512*3
  float* out_newpts = out + 24576;    // 16*512*128

  float* ws = (float*)d_ws;
  float* ws_newxyz = ws;                                        // 24576 f32
  unsigned short* featsbf = (unsigned short*)(ws + 24576);      // 262144*8 u16
  double* momb = (double*)(ws + 1073152);                       // 8*27 f64
  double* s1g  = momb + 216;                                    // 8*64
  double* q1g  = s1g + 512;
  double* s2g  = q1g + 512;                                     // 8*128
  double* q2g  = s2g + 1024;                                    // ends at momb+3288
  unsigned short* wbf0 = (unsigned short*)(ws + 1079728);       // 512 u16
  unsigned short* wbf1 = (unsigned short*)(ws + 1079984);       // 4096 u16
  unsigned short* wbf2 = (unsigned short*)(ws + 1082032);       // 8192 u16

  fps_wconv_kernel<<<NBATCH + 1, 512, 0, stream>>>(xyz, out_newxyz, ws_newxyz,
      w0, w1, w2, wbf0, wbf1, wbf2, momb);
  ball_kernel<<<2048, 256, 0, stream>>>(xyz, pointsf, ws_newxyz, featsbf, momb);
  mlp_kernel<1><<<1024, 256, 0, stream>>>(featsbf, wbf0, wbf1, wbf2, momb,
      g0, be0, g1, be1, g2, be2, s1g, q1g, s2g, q2g, nullptr);
  mlp_kernel<2><<<1024, 256, 0, stream>>>(featsbf, wbf0, wbf1, wbf2, momb,
      g0, be0, g1, be1, g2, be2, s1g, q1g, s2g, q2g, nullptr);
  mlp_kernel<3><<<1024, 256, 0, stream>>>(featsbf, wbf0, wbf1, wbf2, momb,
      g0, be0, g1, be1, g2, be2, s1g, q1g, s2g, q2g, out_newpts);
}

// Round 10
// 433.257 us; speedup vs baseline: 1.0435x; 1.0435x over previous
//
#include <hip/hip_runtime.h>

#define NPT    4096
#define NBATCH 16
#define NS     512
#define KSAMP  32
#define MROWS  (NBATCH*NS*KSAMP)   // 262144
#define RC2    0.04f
#define NZSTAT 3288                // doubles to zero: 216 + 512 + 512 + 1024 + 1024

using bf16x8 = __attribute__((ext_vector_type(8))) short;
using f32x4  = __attribute__((ext_vector_type(4))) float;
using f32x2  = __attribute__((ext_vector_type(2))) float;
#define MFMA16(A,B,C) __builtin_amdgcn_mfma_f32_16x16x32_bf16(A,B,C,0,0,0)

__device__ __forceinline__ unsigned short f2bf(float f) {
  unsigned u = __float_as_uint(f);
  unsigned r = (u + 0x7FFFu + ((u >> 16) & 1u)) >> 16;   // RNE
  return (unsigned short)r;
}
__device__ __forceinline__ float bf2f(unsigned short h) {
  return __uint_as_float(((unsigned)h) << 16);
}
__device__ __forceinline__ void atomAddF64(double* p, double v) {
  unsafeAtomicAdd(p, v);   // hw global_atomic_add_f64
}

// f64-keyed max with DPP source (key hi-word = dist bits >= 0 so u64 order ==
// f64 order). old=0, bound_ctrl=1: disabled/missing lanes contribute 0 (=id).
template<int CTRL>
__device__ __forceinline__ double dpp_max(double v) {
  long long x = __double_as_longlong(v);
  int lo = __builtin_amdgcn_update_dpp(0, (int)(x & 0xFFFFFFFFll), CTRL, 0xf, 0xf, true);
  int hi = __builtin_amdgcn_update_dpp(0, (int)(x >> 32),          CTRL, 0xf, 0xf, true);
  return fmax(v, __hiloint2double(hi, lo));
}

// ---------------------------------------------------------------------------
// K1: blocks 0..15 = FPS (one per batch, 512 thr = 2 waves/SIMD, 8 pts/thread
// as 4 f32x2). Per step: compute (contract-off, numpy-exact) -> DPP wave
// reduce (lane63) -> plain ds_write_b64 to parity slot red[s&1][w] (8
// independent slots; parity avoids cross-step race; all slots rewritten every
// step so no reset) -> ONE barrier -> every thread reads 8 slots (2x double2)
// + 7-max f64 tree -> far.
// [Measured history: this exact config = 269us (R8). Falsified variants:
//  wave0-DPP two-barrier tail 282us (R6); pk-asm + float4 table 290us (R9,
//  VGPR 52->88, asm defeats scheduler); 1024thr 381us (R4); 256thr 346us (R3).]
// Block 16 = weight bf16 conversion + zeroing of the f64 stats region.
// ---------------------------------------------------------------------------
__global__ __launch_bounds__(512) void fps_wconv_kernel(const float* __restrict__ xyz,
                                                        float* __restrict__ out_newxyz,
                                                        float* __restrict__ ws_newxyz,
                                                        const float* __restrict__ w0,
                                                        const float* __restrict__ w1,
                                                        const float* __restrict__ w2,
                                                        unsigned short* __restrict__ wbf0,
                                                        unsigned short* __restrict__ wbf1,
                                                        unsigned short* __restrict__ wbf2,
                                                        double* __restrict__ statz)
{
  const int t = threadIdx.x;
  const int b = blockIdx.x;
  if (b == NBATCH) {
    if (t < 64) {
#pragma unroll
      for (int c = 0; c < 8; ++c)
        wbf0[t*8 + c] = (c < 6) ? f2bf(w0[t*6 + c]) : (unsigned short)0;
    }
    for (int i = t; i < 64*64; i += 512) wbf1[i] = f2bf(w1[i]);
    for (int i = t; i < 128*64; i += 512) wbf2[i] = f2bf(w2[i]);
    for (int i = t; i < NZSTAT; i += 512) statz[i] = 0.0;
    return;
  }

  __shared__ float pts[NPT*3];
  __shared__ float cent[NS*3];
  __shared__ __align__(16) double red[2][8];
  const float* xb = xyz + (size_t)b * NPT * 3;

  { const float4* s4 = (const float4*)xb;
    float4* d4 = (float4*)pts;
    for (int i = t; i < NPT*3/4; i += 512) d4[i] = s4[i]; }
  __syncthreads();

  f32x2 px[4], py[4], pz[4], dist[4];
  unsigned int loc0[4], loc1[4];
#pragma unroll
  for (int j = 0; j < 4; ++j) {
    int i0 = t + (2*j)   * 512;
    int i1 = t + (2*j+1) * 512;
    px[j] = f32x2{pts[i0*3+0], pts[i1*3+0]};
    py[j] = f32x2{pts[i0*3+1], pts[i1*3+1]};
    pz[j] = f32x2{pts[i0*3+2], pts[i1*3+2]};
    dist[j] = f32x2{1e10f, 1e10f};
    loc0[j] = ~(unsigned)i0;
    loc1[j] = ~(unsigned)i1;
  }

  const int lane = t & 63, w = t >> 6;
  int far = 0;
  for (int s = 0; s < NS; ++s) {
    const float cx = pts[far*3+0], cy = pts[far*3+1], cz = pts[far*3+2];
    if (t == 0) { cent[s*3+0] = cx; cent[s*3+1] = cy; cent[s*3+2] = cz; }
    if (s == NS-1) break;

    double best = 0.0;
    {
#pragma clang fp contract(off)
      const f32x2 vcx = {cx, cx}, vcy = {cy, cy}, vcz = {cz, cz};
#pragma unroll
      for (int j = 0; j < 4; ++j) {
        f32x2 dx = px[j] - vcx;
        f32x2 dy = py[j] - vcy;
        f32x2 dz = pz[j] - vcz;
        f32x2 dd = dx*dx + dy*dy + dz*dz;      // contract(off): rn per element
        f32x2 nd;
        nd.x = fminf(dist[j].x, dd.x);
        nd.y = fminf(dist[j].y, dd.y);
        dist[j] = nd;
        unsigned long long k0 = ((unsigned long long)__float_as_uint(nd.x) << 32)
                              | (unsigned long long)loc0[j];
        unsigned long long k1 = ((unsigned long long)__float_as_uint(nd.y) << 32)
                              | (unsigned long long)loc1[j];
        best = fmax(best, __longlong_as_double((long long)k0));
        best = fmax(best, __longlong_as_double((long long)k1));
      }
    }
    best = dpp_max<0x111>(best);   // row_shr:1
    best = dpp_max<0x112>(best);   // row_shr:2
    best = dpp_max<0x114>(best);   // row_shr:4
    best = dpp_max<0x118>(best);   // row_shr:8
    best = dpp_max<0x142>(best);   // row_bcast:15
    best = dpp_max<0x143>(best);   // row_bcast:31 -> lane63 = wave max

    if (lane == 63) red[s & 1][w] = best;      // plain b64 write, own slot
    __syncthreads();
    { const double2* r2 = (const double2*)red[s & 1];
      double2 a = r2[0], b2 = r2[1], c = r2[2], d = r2[3];
      double m = fmax(fmax(fmax(a.x, a.y), fmax(b2.x, b2.y)),
                      fmax(fmax(c.x, c.y), fmax(d.x, d.y)));
      far = (int)(~(unsigned)(unsigned long long)__double_as_longlong(m));
    }
  }
  __syncthreads();
  for (int i = t; i < NS*3; i += 512) {
    float v = cent[i];
    out_newxyz[(size_t)b*NS*3 + i] = v;
    ws_newxyz[(size_t)b*NS*3 + i]  = v;
  }
}

// ---------------------------------------------------------------------------
// K2: ball query (first-32-by-index within radius, pad with first), gather,
// write feats bf16 [262144][8], accumulate moments of the ROUNDED values into
// 8 f64 buckets via hw atomics. Distance exactly replicates numpy op order.
// ---------------------------------------------------------------------------
__global__ __launch_bounds__(256) void ball_kernel(const float* __restrict__ xyz,
                                                   const float* __restrict__ pointsf,
                                                   const float* __restrict__ ws_newxyz,
                                                   unsigned short* __restrict__ featsbf,
                                                   double* __restrict__ momb)
{
  __shared__ int sel[4][KSAMP];
  __shared__ float momw[4][27];
  const int t = threadIdx.x, lane = t & 63, w = t >> 6;
  const int q = blockIdx.x * 4 + w;         // 0..8191
  const int b = q >> 9;
  const float* xb = xyz     + (size_t)b * NPT * 3;
  const float* pb = pointsf + (size_t)b * NPT * 3;

  const float qx = ws_newxyz[q*3+0], qy = ws_newxyz[q*3+1], qz = ws_newxyz[q*3+2];
  const float q2 = __fadd_rn(__fadd_rn(__fmul_rn(qx,qx), __fmul_rn(qy,qy)), __fmul_rn(qz,qz));

  int count = 0;
  for (int c = 0; c < 64 && count < KSAMP; ++c) {
    int i = (c << 6) + lane;
    float fx = xb[i*3+0], fy = xb[i*3+1], fz = xb[i*3+2];
    float p2 = __fadd_rn(__fadd_rn(__fmul_rn(fx,fx), __fmul_rn(fy,fy)), __fmul_rn(fz,fz));
    float e  = __fadd_rn(__fadd_rn(__fmul_rn(qx,fx), __fmul_rn(qy,fy)), __fmul_rn(qz,fz));
    float d  = __fadd_rn(__fadd_rn(__fmul_rn(-2.0f, e), q2), p2);
    bool keep = (d <= RC2);
    unsigned long long mask = __ballot(keep ? 1 : 0);
    int slot = count + (int)__popcll(mask & ((1ull << lane) - 1ull));
    if (keep && slot < KSAMP) sel[w][slot] = i;
    count += (int)__popcll(mask);
  }
  __syncthreads();

  float f[6];
  const int n = (count < KSAMP) ? count : KSAMP;
  if (lane < KSAMP) {
    int id = (lane < n) ? sel[w][lane] : sel[w][0];
    float gx = xb[id*3+0], gy = xb[id*3+1], gz = xb[id*3+2];
    unsigned short hb[8];
    hb[0] = f2bf(__fsub_rn(gx, qx));
    hb[1] = f2bf(__fsub_rn(gy, qy));
    hb[2] = f2bf(__fsub_rn(gz, qz));
    hb[3] = f2bf(pb[id*3+0]);
    hb[4] = f2bf(pb[id*3+1]);
    hb[5] = f2bf(pb[id*3+2]);
    uint4 pk;
    pk.x = (unsigned)hb[0] | ((unsigned)hb[1] << 16);
    pk.y = (unsigned)hb[2] | ((unsigned)hb[3] << 16);
    pk.z = (unsigned)hb[4] | ((unsigned)hb[5] << 16);
    pk.w = 0;
    ((uint4*)featsbf)[(size_t)q * KSAMP + lane] = pk;
#pragma unroll
    for (int c2 = 0; c2 < 6; ++c2) f[c2] = bf2f(hb[c2]);
  } else {
    f[0]=f[1]=f[2]=f[3]=f[4]=f[5]=0.f;
  }

  float p[27];
#pragma unroll
  for (int c = 0; c < 6; ++c) p[c] = f[c];
  { int m = 6;
#pragma unroll
    for (int c = 0; c < 6; ++c)
#pragma unroll
      for (int d = c; d < 6; ++d) p[m++] = f[c]*f[d]; }
#pragma unroll
  for (int mm = 0; mm < 27; ++mm) {
    float v = p[mm];
#pragma unroll
    for (int off = 1; off < 64; off <<= 1) v += __shfl_xor(v, off);
    p[mm] = v;
  }
  if (lane == 0) {
#pragma unroll
    for (int mm = 0; mm < 27; ++mm) momw[w][mm] = p[mm];
  }
  __syncthreads();
  if (t < 27)
    atomAddF64(&momb[(blockIdx.x & 7)*27 + t],
               (double)(momw[0][t] + momw[1][t] + momw[2][t] + momw[3][t]));
}

// ---------------------------------------------------------------------------
// MLP via bf16 MFMA 16x16x32. Block = 256 rows (8 queries), 4 waves.
// Per-block BN scale/shift prologue from global f64 stat buckets:
//   L0: analytic from 27 moments of rounded feats x rounded W0.
//   L1/L2: mean/var from bucketed sum/sumsq of raw accumulators.
// PASS 1: L0,L1 -> bucket-atomics stats(L1).
// PASS 2: L0,L1,L2 -> bucket-atomics stats(L2).
// PASS 3: L0,L1,L2 -> bn2+relu+max over k=32 -> out.
// ---------------------------------------------------------------------------
template<int PASS>
__global__ __launch_bounds__(256) void mlp_kernel(
    const unsigned short* __restrict__ featsbf,
    const unsigned short* __restrict__ wbf0,
    const unsigned short* __restrict__ wbf1,
    const unsigned short* __restrict__ wbf2,
    const double* __restrict__ momb,
    const float* __restrict__ g0, const float* __restrict__ be0,
    const float* __restrict__ g1, const float* __restrict__ be1,
    const float* __restrict__ g2, const float* __restrict__ be2,
    double* __restrict__ s1g, double* __restrict__ q1g,
    double* __restrict__ s2g, double* __restrict__ q2g,
    float* __restrict__ outp)
{
  __shared__ __align__(16) unsigned short xb[256*72];   // 36864 B
  __shared__ __align__(16) unsigned short wb[128*72];   // 18432 B
  constexpr int SN = (PASS==1) ? 4*64 : (PASS==2 ? 4*128 : 1);
  __shared__ float ssum[SN], sqsum[SN];
  __shared__ float ssc0[64], ssh0[64], ssc1[64], ssh1[64], ssc2[128], ssh2[128];
  __shared__ double mom[27];

  unsigned short* wb0 = wb + 64*72;   // [64][8]  bf16 overlay
  unsigned short* xf  = wb + 72*72;   // [256][8] bf16 overlay

  const int t = threadIdx.x, blk = blockIdx.x;
  const int lane = t & 63, w = t >> 6;
  const int lr = lane & 15, lk = lane >> 4;

  // ---- staging + moment bucket sum ----
  ((uint4*)xf)[t] = ((const uint4*)featsbf)[(size_t)blk*256 + t];
  if (t < 64) ((uint4*)wb0)[t] = ((const uint4*)wbf0)[t];
  { int row = t >> 2, seg = t & 3;   // W1: 64 rows x 128 B
    const uint4* src = (const uint4*)(wbf1 + row*64 + seg*16);
    uint4* dst = (uint4*)(wb + row*72 + seg*16);
    dst[0] = src[0]; dst[1] = src[1]; }
  if (t < 27) {
    double s = 0.0;
#pragma unroll
    for (int bkt = 0; bkt < 8; ++bkt) s += momb[bkt*27 + t];
    mom[t] = s / (double)MROWS;
  }
  __syncthreads();

  // ---- per-block BN scale/shift prologue ----
  if (t < 64) {
    double wv[6];
#pragma unroll
    for (int c = 0; c < 6; ++c) wv[c] = (double)bf2f(wbf0[t*8 + c]);
    double macc = 0.0;
#pragma unroll
    for (int c = 0; c < 6; ++c) macc += wv[c] * mom[c];
    double e2 = 0.0;
    int mi = 6;
#pragma unroll
    for (int c = 0; c < 6; ++c)
#pragma unroll
      for (int d = c; d < 6; ++d) {
        double coef = (c == d) ? wv[c]*wv[c] : 2.0*wv[c]*wv[d];
        e2 += coef * mom[mi++];
      }
    double var = e2 - macc*macc;
    float sc = g0[t] / sqrtf((float)var + 1e-5f);
    ssc0[t] = sc;
    ssh0[t] = be0[t] - (float)macc * sc;
  }
  if (PASS >= 2 && t < 64) {
    double s = 0.0, qq = 0.0;
#pragma unroll
    for (int bkt = 0; bkt < 8; ++bkt) { s += s1g[bkt*64 + t]; qq += q1g[bkt*64 + t]; }
    double mean = s / (double)MROWS;
    double var  = qq / (double)MROWS - mean*mean;
    float sc = g1[t] / sqrtf((float)var + 1e-5f);
    ssc1[t] = sc;
    ssh1[t] = be1[t] - (float)mean * sc;
  }
  if (PASS == 3 && t < 128) {
    double s = 0.0, qq = 0.0;
#pragma unroll
    for (int bkt = 0; bkt < 8; ++bkt) { s += s2g[bkt*128 + t]; qq += q2g[bkt*128 + t]; }
    double mean = s / (double)MROWS;
    double var  = qq / (double)MROWS - mean*mean;
    float sc = g2[t] / sqrtf((float)var + 1e-5f);
    ssc2[t] = sc;
    ssh2[t] = be2[t] - (float)mean * sc;
  }
  __syncthreads();

  const bf16x8 zb = {0,0,0,0,0,0,0,0};
  const f32x4 fz = {0.f,0.f,0.f,0.f};

  // ---- L0 ----
  f32x4 acc[16];
#pragma unroll
  for (int i = 0; i < 16; ++i) acc[i] = fz;
  {
    bf16x8 af[4], bw[4];
#pragma unroll
    for (int i = 0; i < 4; ++i) { af[i] = zb; bw[i] = zb; }
    if (lk == 0) {
#pragma unroll
      for (int rt = 0; rt < 4; ++rt) af[rt] = *(const bf16x8*)&xf[(w*64 + rt*16 + lr)*8];
#pragma unroll
      for (int ct = 0; ct < 4; ++ct) bw[ct] = *(const bf16x8*)&wb0[(ct*16 + lr)*8];
    }
#pragma unroll
    for (int rt = 0; rt < 4; ++rt)
#pragma unroll
      for (int ct = 0; ct < 4; ++ct) acc[rt*4+ct] = MFMA16(af[rt], bw[ct], acc[rt*4+ct]);
  }
#pragma unroll
  for (int rt = 0; rt < 4; ++rt)
#pragma unroll
    for (int ct = 0; ct < 4; ++ct) {
      const int ch = ct*16 + lr;
      const float sc = ssc0[ch], sh = ssh0[ch];
#pragma unroll
      for (int r = 0; r < 4; ++r) {
        const int row = w*64 + rt*16 + lk*4 + r;
        float v = fmaxf(fmaf(acc[rt*4+ct][r], sc, sh), 0.f);
        xb[row*72 + ch] = f2bf(v);
      }
    }
  __syncthreads();

  // ---- L1 ----
  f32x4 acc1[16];
#pragma unroll
  for (int i = 0; i < 16; ++i) acc1[i] = fz;
#pragma unroll
  for (int k0 = 0; k0 < 64; k0 += 32) {
    bf16x8 af[4], bw[4];
#pragma unroll
    for (int rt = 0; rt < 4; ++rt) af[rt] = *(const bf16x8*)&xb[(w*64 + rt*16 + lr)*72 + k0 + lk*8];
#pragma unroll
    for (int ct = 0; ct < 4; ++ct) bw[ct] = *(const bf16x8*)&wb[(ct*16 + lr)*72 + k0 + lk*8];
#pragma unroll
    for (int rt = 0; rt < 4; ++rt)
#pragma unroll
      for (int ct = 0; ct < 4; ++ct) acc1[rt*4+ct] = MFMA16(af[rt], bw[ct], acc1[rt*4+ct]);
  }

  if constexpr (PASS == 1) {
#pragma unroll
    for (int ct = 0; ct < 4; ++ct) {
      float s = 0.f, q = 0.f;
#pragma unroll
      for (int rt = 0; rt < 4; ++rt)
#pragma unroll
        for (int r = 0; r < 4; ++r) { float v = acc1[rt*4+ct][r]; s += v; q = fmaf(v, v, q); }
      s += __shfl_xor(s, 16); s += __shfl_xor(s, 32);
      q += __shfl_xor(q, 16); q += __shfl_xor(q, 32);
      if (lk == 0) { ssum[w*64 + ct*16 + lr] = s; sqsum[w*64 + ct*16 + lr] = q; }
    }
    __syncthreads();
    if (t < 64) {
      float s = ssum[t] + ssum[64+t] + ssum[128+t] + ssum[192+t];
      float q = sqsum[t] + sqsum[64+t] + sqsum[128+t] + sqsum[192+t];
      const int bkt = blk & 7;
      atomAddF64(&s1g[bkt*64 + t], (double)s);
      atomAddF64(&q1g[bkt*64 + t], (double)q);
    }
    return;
  }

  __syncthreads();

  { int row = t >> 1, seg = t & 1;   // W2: 128 rows x 128 B
    const uint4* src = (const uint4*)(wbf2 + row*64 + seg*32);
    uint4* dst = (uint4*)(wb + row*72 + seg*32);
    dst[0] = src[0]; dst[1] = src[1]; dst[2] = src[2]; dst[3] = src[3]; }
#pragma unroll
  for (int rt = 0; rt < 4; ++rt)
#pragma unroll
    for (int ct = 0; ct < 4; ++ct) {
      const int ch = ct*16 + lr;
      const float sc = ssc1[ch], sh = ssh1[ch];
#pragma unroll
      for (int r = 0; r < 4; ++r) {
        const int row = w*64 + rt*16 + lk*4 + r;
        float v = fmaxf(fmaf(acc1[rt*4+ct][r], sc, sh), 0.f);
        xb[row*72 + ch] = f2bf(v);
      }
    }
  __syncthreads();

  // ---- L2 ----
#pragma unroll
  for (int half = 0; half < 2; ++half) {
    f32x4 acc2[16];
#pragma unroll
    for (int i = 0; i < 16; ++i) acc2[i] = fz;
#pragma unroll
    for (int k0 = 0; k0 < 64; k0 += 32) {
      bf16x8 af[4], bw[4];
#pragma unroll
      for (int rt = 0; rt < 4; ++rt) af[rt] = *(const bf16x8*)&xb[(w*64 + rt*16 + lr)*72 + k0 + lk*8];
#pragma unroll
      for (int ct = 0; ct < 4; ++ct) bw[ct] = *(const bf16x8*)&wb[((half*4+ct)*16 + lr)*72 + k0 + lk*8];
#pragma unroll
      for (int rt = 0; rt < 4; ++rt)
#pragma unroll
        for (int ct = 0; ct < 4; ++ct) acc2[rt*4+ct] = MFMA16(af[rt], bw[ct], acc2[rt*4+ct]);
    }
    if constexpr (PASS == 2) {
#pragma unroll
      for (int ct = 0; ct < 4; ++ct) {
        float s = 0.f, q = 0.f;
#pragma unroll
        for (int rt = 0; rt < 4; ++rt)
#pragma unroll
          for (int r = 0; r < 4; ++r) { float v = acc2[rt*4+ct][r]; s += v; q = fmaf(v, v, q); }
        s += __shfl_xor(s, 16); s += __shfl_xor(s, 32);
        q += __shfl_xor(q, 16); q += __shfl_xor(q, 32);
        const int ch = (half*4+ct)*16 + lr;
        if (lk == 0) { ssum[w*128 + ch] = s; sqsum[w*128 + ch] = q; }
      }
    } else {
#pragma unroll
      for (int ct = 0; ct < 4; ++ct) {
        const int ch = (half*4+ct)*16 + lr;
        const float sc = ssc2[ch], sh = ssh2[ch];
        float ma = 0.f, mb = 0.f;   // relu floor
#pragma unroll
        for (int r = 0; r < 4; ++r) {
          ma = fmaxf(ma, fmaf(acc2[0*4+ct][r], sc, sh));
          ma = fmaxf(ma, fmaf(acc2[1*4+ct][r], sc, sh));
          mb = fmaxf(mb, fmaf(acc2[2*4+ct][r], sc, sh));
          mb = fmaxf(mb, fmaf(acc2[3*4+ct][r], sc, sh));
        }
        ma = fmaxf(ma, __shfl_xor(ma, 16)); ma = fmaxf(ma, __shfl_xor(ma, 32));
        mb = fmaxf(mb, __shfl_xor(mb, 16)); mb = fmaxf(mb, __shfl_xor(mb, 32));
        if (lk == 0) {
          const int q0 = blk*8 + w*2;
          outp[(size_t)q0*128 + ch]     = ma;
          outp[(size_t)(q0+1)*128 + ch] = mb;
        }
      }
    }
  }
  if constexpr (PASS == 2) {
    __syncthreads();
    if (t < 128) {
      float s = ssum[t] + ssum[128+t] + ssum[256+t] + ssum[384+t];
      float q = sqsum[t] + sqsum[128+t] + sqsum[256+t] + sqsum[384+t];
      const int bkt = blk & 7;
      atomAddF64(&s2g[bkt*128 + t], (double)s);
      atomAddF64(&q2g[bkt*128 + t], (double)q);
    }
  }
}

// ---------------------------------------------------------------------------
extern "C" void kernel_launch(void* const* d_in, const int* in_sizes, int n_in,
                              void* d_out, int out_size, void* d_ws, size_t ws_size,
                              hipStream_t stream)
{
  const float* xyz     = (const float*)d_in[0];
  const float* pointsf = (const float*)d_in[1];
  const float* w0  = (const float*)d_in[2];
  const float* g0  = (const float*)d_in[4];
  const float* be0 = (const float*)d_in[5];
  const float* w1  = (const float*)d_in[6];
  const float* g1  = (const float*)d_in[8];
  const float* be1 = (const float*)d_in[9];
  const float* w2  = (const float*)d_in[10];
  const float* g2  = (const float*)d_in[12];
  const float* be2 = (const float*)d_in[13];

  float* out        = (float*)d_out;
  float* out_newxyz = out;            // 16*512*3
  float* out_newpts = out + 24576;    // 16*512*128

  float* ws = (float*)d_ws;
  float* ws_newxyz = ws;                                        // 24576 f32
  unsigned short* featsbf = (unsigned short*)(ws + 24576);      // 262144*8 u16
  double* momb = (double*)(ws + 1073152);                       // 8*27 f64
  double* s1g  = momb + 216;                                    // 8*64
  double* q1g  = s1g + 512;
  double* s2g  = q1g + 512;                                     // 8*128
  double* q2g  = s2g + 1024;                                    // ends at momb+3288
  unsigned short* wbf0 = (unsigned short*)(ws + 1079728);       // 512 u16
  unsigned short* wbf1 = (unsigned short*)(ws + 1079984);       // 4096 u16
  unsigned short* wbf2 = (unsigned short*)(ws + 1082032);       // 8192 u16

  fps_wconv_kernel<<<NBATCH + 1, 512, 0, stream>>>(xyz, out_newxyz, ws_newxyz,
      w0, w1, w2, wbf0, wbf1, wbf2, momb);
  ball_kernel<<<2048, 256, 0, stream>>>(xyz, pointsf, ws_newxyz, featsbf, momb);
  mlp_kernel<1><<<1024, 256, 0, stream>>>(featsbf, wbf0, wbf1, wbf2, momb,
      g0, be0, g1, be1, g2, be2, s1g, q1g, s2g, q2g, nullptr);
  mlp_kernel<2><<<1024, 256, 0, stream>>>(featsbf, wbf0, wbf1, wbf2, momb,
      g0, be0, g1, be1, g2, be2, s1g, q1g, s2g, q2g, nullptr);
  mlp_kernel<3><<<1024, 256, 0, stream>>>(featsbf, wbf0, wbf1, wbf2, momb,
      g0, be0, g1, be1, g2, be2, s1g, q1g, s2g, q2g, out_newpts);
}